// Round 1
// baseline (223.788 us; speedup 1.0000x reference)
//
#include <hip/hip_runtime.h>

// Signature-kernel MMD via Goursat PDE.
// X: (64,128,16) f32, Y: (64,128,16) f32, n=0 (f=1).
// For each pair, solve 127x127 PDE: G[i+1][j+1]=G[i+1][j]+G[i][j+1]+G[i][j]*(inc-1),
// inc[i][j] = dot(dX_i, dY_j), D=16. Output scalar mean(kxx)+mean(kyy)-2*mean(kxy).
//
// Parallelization: one wave (block of 64) per (gram, a, b) task.
// Row update = elementwise c[j] then prefix-sum across 127 columns (2 cols/lane).
// Gram symmetry: k(a,b)=k(b,a) exactly -> XX/YY lower triangles skipped, weight 2.

#define NTASKS (3 * 4096)

__global__ __launch_bounds__(64) void sig_pde_kernel(
    const float* __restrict__ X, const float* __restrict__ Y,
    float* __restrict__ ws)
{
    __shared__ float Xs[2048];  // X[a] rows (128x16), then in-place dX (127x16)

    const int T = blockIdx.x;
    const int g = T >> 12;        // 0:XX 1:YY 2:XY
    const int t = T & 4095;
    const int a = t >> 6, b = t & 63;
    const int lane = threadIdx.x;

    // symmetric grams: only upper triangle (a<=b), weight doubled off-diagonal
    if (g < 2 && a > b) { if (lane == 0) ws[T] = 0.0f; return; }

    const float* P = (g == 1) ? Y : X;   // row paths  (index a)
    const float* Q = (g == 0) ? X : Y;   // col paths  (index b)
    const float weight = (g == 2) ? (-2.0f / 4096.0f)
                                  : ((a == b ? 1.0f : 2.0f) / 4096.0f);

    // ---- stage P[a] (128x16 f32 = 8KB) into LDS, coalesced float4 ----
    {
        const float4* Pa = (const float4*)(P + a * 2048);
        float4* Xs4 = (float4*)Xs;
#pragma unroll
        for (int k = 0; k < 8; ++k)
            Xs4[lane + (k << 6)] = Pa[lane + (k << 6)];
    }
    __syncthreads();

    // ---- in-place diff: dX[i][d] = X[i+1][d]-X[i][d]; flat: Xs[i]=Xs[i+16]-Xs[i], i<2032
    {
        float tmp[32];
#pragma unroll
        for (int k = 0; k < 32; ++k) {
            int idx = lane + (k << 6);
            tmp[k] = (idx < 2032) ? (Xs[idx + 16] - Xs[idx]) : 0.0f;
        }
        __syncthreads();
#pragma unroll
        for (int k = 0; k < 32; ++k) {
            int idx = lane + (k << 6);
            if (idx < 2032) Xs[idx] = tmp[k];
        }
    }
    __syncthreads();

    // ---- per-lane dY rows j=2*lane, 2*lane+1 into registers ----
    float y0[16], y1[16];
    {
        const float* Qb = Q + b * 2048;
        const int r0 = lane << 1;                   // 0..126
        const int r2 = (r0 + 2 > 127) ? 127 : (r0 + 2);  // lane 63 clamp (c1 masked)
        const float4* A4 = (const float4*)(Qb + r0 * 16);
        const float4* B4 = (const float4*)(Qb + (r0 + 1) * 16);
        const float4* C4 = (const float4*)(Qb + r2 * 16);
#pragma unroll
        for (int q = 0; q < 4; ++q) {
            float4 ra = A4[q], rb = B4[q], rc = C4[q];
            y0[4 * q + 0] = rb.x - ra.x;  y1[4 * q + 0] = rc.x - rb.x;
            y0[4 * q + 1] = rb.y - ra.y;  y1[4 * q + 1] = rc.y - rb.y;
            y0[4 * q + 2] = rb.z - ra.z;  y1[4 * q + 2] = rc.z - rb.z;
            y0[4 * q + 3] = rb.w - ra.w;  y1[4 * q + 3] = rc.w - rb.w;
        }
    }

    // ---- PDE rows. Lane l holds G[r][2l+1] (g_lo) and G[r][2l+2] (g_hi). ----
    float g_lo = 1.0f, g_hi = 1.0f;
    const bool last = (lane == 63);   // column 127 is its g_lo; c1 (col 128) masked

    for (int r = 0; r < 127; ++r) {
        // wave-uniform dX row r (broadcast LDS reads, no bank conflicts)
        const float4* xr4 = (const float4*)(Xs + r * 16);
        float4 x0 = xr4[0], x1 = xr4[1], x2 = xr4[2], x3 = xr4[3];

        float inc0, inc1;
        {
            float s0 = x0.x * y0[0], s1 = x0.y * y0[1];
            s0 = fmaf(x0.z, y0[2], s0);  s1 = fmaf(x0.w, y0[3], s1);
            s0 = fmaf(x1.x, y0[4], s0);  s1 = fmaf(x1.y, y0[5], s1);
            s0 = fmaf(x1.z, y0[6], s0);  s1 = fmaf(x1.w, y0[7], s1);
            s0 = fmaf(x2.x, y0[8], s0);  s1 = fmaf(x2.y, y0[9], s1);
            s0 = fmaf(x2.z, y0[10], s0); s1 = fmaf(x2.w, y0[11], s1);
            s0 = fmaf(x3.x, y0[12], s0); s1 = fmaf(x3.y, y0[13], s1);
            s0 = fmaf(x3.z, y0[14], s0); s1 = fmaf(x3.w, y0[15], s1);
            inc0 = s0 + s1;
        }
        {
            float s0 = x0.x * y1[0], s1 = x0.y * y1[1];
            s0 = fmaf(x0.z, y1[2], s0);  s1 = fmaf(x0.w, y1[3], s1);
            s0 = fmaf(x1.x, y1[4], s0);  s1 = fmaf(x1.y, y1[5], s1);
            s0 = fmaf(x1.z, y1[6], s0);  s1 = fmaf(x1.w, y1[7], s1);
            s0 = fmaf(x2.x, y1[8], s0);  s1 = fmaf(x2.y, y1[9], s1);
            s0 = fmaf(x2.z, y1[10], s0); s1 = fmaf(x2.w, y1[11], s1);
            s0 = fmaf(x3.x, y1[12], s0); s1 = fmaf(x3.y, y1[13], s1);
            s0 = fmaf(x3.z, y1[14], s0); s1 = fmaf(x3.w, y1[15], s1);
            inc1 = s0 + s1;
        }

        // left neighbor's G[r][2l] (lane l-1's g_hi); lane 0 boundary = 1
        float gl = __shfl_up(g_hi, 1, 64);
        if (lane == 0) gl = 1.0f;

        // c[j] = G[r][j+1] + G[r][j]*(inc-1)
        float c0 = fmaf(gl, inc0 - 1.0f, g_lo);       // j = 2l
        float c1 = last ? 0.0f
                        : fmaf(g_lo, inc1 - 1.0f, g_hi);  // j = 2l+1
        float s = c0 + c1;

        // inclusive prefix sum of s across the wave
#pragma unroll
        for (int d = 1; d < 64; d <<= 1) {
            float u = __shfl_up(s, d, 64);
            if (lane >= d) s += u;
        }

        // G[r+1][2l+1] = 1 + (excl + c0) = 1 + S - c1 ; G[r+1][2l+2] = 1 + S
        g_lo = (s - c1) + 1.0f;
        g_hi = s + 1.0f;
    }

    // result k(a,b) = G[127][127] = lane 63's g_lo
    float kab = __shfl(g_lo, 63, 64);
    if (lane == 0) ws[T] = weight * kab;
}

__global__ __launch_bounds__(256) void sig_reduce_kernel(
    const float* __restrict__ ws, float* __restrict__ out)
{
    __shared__ float red[256];
    float s = 0.0f;
    for (int i = threadIdx.x; i < NTASKS; i += 256) s += ws[i];
    red[threadIdx.x] = s;
    __syncthreads();
    for (int st = 128; st > 0; st >>= 1) {
        if (threadIdx.x < st) red[threadIdx.x] += red[threadIdx.x + st];
        __syncthreads();
    }
    if (threadIdx.x == 0) out[0] = red[0];
}

extern "C" void kernel_launch(void* const* d_in, const int* in_sizes, int n_in,
                              void* d_out, int out_size, void* d_ws, size_t ws_size,
                              hipStream_t stream) {
    const float* X = (const float*)d_in[0];
    const float* Y = (const float*)d_in[1];
    // d_in[2] is n; harness always uses n=0 -> f=1 (no refinement)
    float* out = (float*)d_out;
    float* ws  = (float*)d_ws;   // NTASKS floats, every slot written each call

    sig_pde_kernel<<<NTASKS, 64, 0, stream>>>(X, Y, ws);
    sig_reduce_kernel<<<1, 256, 0, stream>>>(ws, out);
}

// Round 2
// 149.448 us; speedup vs baseline: 1.4974x; 1.4974x over previous
//
#include <hip/hip_runtime.h>

// Signature-kernel MMD via Goursat PDE — round 2.
// Round-1 postmortem: __shfl-based scan lowered to ds_bpermute (LDS pipe,
// per-CU, ~11 LDS ops/row/wave) -> LDS-pipe bound at 175us, VALUBusy 41%.
// Round-2: (1) DPP VALU scan (row_shr 1/2/4/8 + row_bcast 15/31), wave_shr:1
// for the neighbor fetch -> zero LDS ops in the K-loop. (2) dX/dY increments
// precomputed to ws; PDE kernel reads block-uniform dX rows as scalar loads
// (s_load_dwordx16 -> SGPR operands to the FMAs). (3) compact task grid:
// 4-wave blocks sharing one row-path, no dead triangle blocks.

#define XY_BLOCKS 1024
#define TRI_BLOCKS 544
#define NBLOCKS (XY_BLOCKS + 2 * TRI_BLOCKS)   // 2112
#define DINC_PER 130048                         // 64*127*16 floats
#define WS_OUT_OFF (2 * DINC_PER)               // 260096 floats
#define NOUT (NBLOCKS * 4)                      // 8448 result slots

template <int C, int RM, int BM, bool BC>
__device__ __forceinline__ float dpp0(float x) {
    return __builtin_bit_cast(float, __builtin_amdgcn_update_dpp(
        0, __builtin_bit_cast(int, x), C, RM, BM, BC));
}

// 64-lane inclusive prefix sum, pure VALU (6 dependent adds).
__device__ __forceinline__ float wave_scan_incl(float v) {
    v += dpp0<0x111, 0xf, 0xf, true>(v);   // row_shr:1
    v += dpp0<0x112, 0xf, 0xf, true>(v);   // row_shr:2
    v += dpp0<0x114, 0xf, 0xf, true>(v);   // row_shr:4
    v += dpp0<0x118, 0xf, 0xf, true>(v);   // row_shr:8
    v += dpp0<0x142, 0xa, 0xf, false>(v);  // row_bcast:15 -> rows 1,3
    v += dpp0<0x143, 0xc, 0xf, false>(v);  // row_bcast:31 -> rows 2,3
    return v;
}

// lane l gets lane l-1's x; lane 0 gets `oldv`.
__device__ __forceinline__ float wave_shr1(float x, float oldv) {
    return __builtin_bit_cast(float, __builtin_amdgcn_update_dpp(
        __builtin_bit_cast(int, oldv), __builtin_bit_cast(int, x),
        0x138, 0xf, 0xf, false));          // wave_shr:1
}

// ---- kernel 1: path increments X,Y -> ws (dX at 0, dY at DINC_PER) ----
__global__ __launch_bounds__(256) void sig_diff(
    const float* __restrict__ X, const float* __restrict__ Y,
    float* __restrict__ dInc)
{
    int i = blockIdx.x * 256 + threadIdx.x;   // float4 id, 65024 total
    if (i >= 65024) return;
    int which = (i >= 32512) ? 1 : 0;
    int j = i - which * 32512;
    int a = j / 508;                          // 127*4 float4 per path
    int rq = j - a * 508;                     // r*4 + q
    const float* S = which ? Y : X;
    const float4* p = (const float4*)(S + a * 2048) + rq;
    float4 v0 = p[0], v1 = p[4];              // +16 floats = next row
    float4 d;
    d.x = v1.x - v0.x; d.y = v1.y - v0.y;
    d.z = v1.z - v0.z; d.w = v1.w - v0.w;
    ((float4*)dInc)[i] = d;
}

// ---- kernel 2: PDE. 4 waves/block, one (gram, a) per block, b = b0+wave ----
__global__ __launch_bounds__(256) void sig_pde2(
    const float* __restrict__ dInc, float* __restrict__ outw)
{
    const int B = blockIdx.x;
    const int w = threadIdx.x >> 6, lane = threadIdx.x & 63;

    int g, a, b0;
    if (B < XY_BLOCKS) {                       // XY gram: dense
        g = 2; a = B >> 4; b0 = (B & 15) << 2;
    } else {                                   // XX / YY: upper triangle
        int t = B - XY_BLOCKS; g = 0;
        if (t >= TRI_BLOCKS) { t -= TRI_BLOCKS; g = 1; }
        int aa = 0;
        for (;;) { int nb = (67 - aa) >> 2; if (t < nb) break; t -= nb; ++aa; }
        a = aa; b0 = aa + (t << 2);
    }
    const int b = b0 + w;
    const int slot = (B << 2) + w;
    if (g < 2 && b > 63) { if (lane == 0) outw[slot] = 0.0f; return; }

    const float* dXb = dInc;
    const float* dYb = dInc + DINC_PER;
    const float* dA = (g == 1) ? dYb : dXb;    // row paths
    const float* dB = (g == 0) ? dXb : dYb;    // col paths
    const float weight = (g == 2) ? (-2.0f / 4096.0f)
                                  : ((a == b ? 1.0f : 2.0f) / 4096.0f);

    // per-lane dY rows j=2l, 2l+1 (lane 63's second row is masked via c1)
    float ya[16], yb_[16];
    {
        const float* Qb = dB + b * 2032;
        const int j0 = lane << 1;
        const int j1 = (j0 + 1 < 127) ? j0 + 1 : 126;
        const float4* A4 = (const float4*)(Qb + j0 * 16);
        const float4* B4 = (const float4*)(Qb + j1 * 16);
#pragma unroll
        for (int q = 0; q < 4; ++q) {
            float4 va = A4[q], vb = B4[q];
            ya[4*q+0] = va.x; ya[4*q+1] = va.y; ya[4*q+2] = va.z; ya[4*q+3] = va.w;
            yb_[4*q+0] = vb.x; yb_[4*q+1] = vb.y; yb_[4*q+2] = vb.z; yb_[4*q+3] = vb.w;
        }
    }

    // block-uniform dX base -> scalar loads (s_load) for each row
    const int abase = __builtin_amdgcn_readfirstlane(a * 2032);
    const float4* Ar = (const float4*)(dA + abase);

    float xr[16], xn[16];
#pragma unroll
    for (int q = 0; q < 4; ++q) {
        float4 v = Ar[q];
        xr[4*q+0] = v.x; xr[4*q+1] = v.y; xr[4*q+2] = v.z; xr[4*q+3] = v.w;
    }

    float g_lo = 1.0f, g_hi = 1.0f;            // G[r][2l+1], G[r][2l+2]
    const bool last = (lane == 63);

    for (int r = 0; r < 127; ++r) {
        // prefetch next dX row (uniform -> SGPRs), hidden under this row's math
        const int rn = (r < 126) ? r + 1 : 126;
#pragma unroll
        for (int q = 0; q < 4; ++q) {
            float4 v = Ar[4 * rn + q];
            xn[4*q+0] = v.x; xn[4*q+1] = v.y; xn[4*q+2] = v.z; xn[4*q+3] = v.w;
        }
        // inc - 1 via accumulators seeded with -0.5 each (2 chains per dot)
        float s0 = -0.5f, s1 = -0.5f, t0 = -0.5f, t1 = -0.5f;
#pragma unroll
        for (int d = 0; d < 16; d += 2) {
            s0 = fmaf(xr[d], ya[d], s0);    s1 = fmaf(xr[d+1], ya[d+1], s1);
            t0 = fmaf(xr[d], yb_[d], t0);   t1 = fmaf(xr[d+1], yb_[d+1], t1);
        }
        const float i0 = s0 + s1;              // inc(r, 2l)   - 1
        const float i1 = t0 + t1;              // inc(r, 2l+1) - 1

        const float gl = wave_shr1(g_hi, 1.0f);         // G[r][2l], lane0 -> 1
        const float c0 = fmaf(gl, i0, g_lo);
        const float c1 = last ? 0.0f : fmaf(g_lo, i1, g_hi);
        const float S = wave_scan_incl(c0 + c1);
        g_lo = (S - c1) + 1.0f;
        g_hi = S + 1.0f;
#pragma unroll
        for (int d = 0; d < 16; ++d) xr[d] = xn[d];
    }

    const float kab = __builtin_bit_cast(float,
        __builtin_amdgcn_readlane(__builtin_bit_cast(int, g_lo), 63));
    if (lane == 0) outw[slot] = weight * kab;
}

__global__ __launch_bounds__(256) void sig_reduce2(
    const float* __restrict__ v, float* __restrict__ out, int n)
{
    __shared__ float red[256];
    float s = 0.0f;
    for (int i = threadIdx.x; i < n; i += 256) s += v[i];
    red[threadIdx.x] = s;
    __syncthreads();
    for (int st = 128; st > 0; st >>= 1) {
        if (threadIdx.x < st) red[threadIdx.x] += red[threadIdx.x + st];
        __syncthreads();
    }
    if (threadIdx.x == 0) out[0] = red[0];
}

// ---- fallback (ws too small for increment staging): round-1 kernel ----
__global__ __launch_bounds__(64) void sig_pde_kernel(
    const float* __restrict__ X, const float* __restrict__ Y,
    float* __restrict__ ws)
{
    __shared__ float Xs[2048];
    const int T = blockIdx.x;
    const int g = T >> 12;
    const int t = T & 4095;
    const int a = t >> 6, b = t & 63;
    const int lane = threadIdx.x;
    if (g < 2 && a > b) { if (lane == 0) ws[T] = 0.0f; return; }
    const float* P = (g == 1) ? Y : X;
    const float* Q = (g == 0) ? X : Y;
    const float weight = (g == 2) ? (-2.0f / 4096.0f)
                                  : ((a == b ? 1.0f : 2.0f) / 4096.0f);
    {
        const float4* Pa = (const float4*)(P + a * 2048);
        float4* Xs4 = (float4*)Xs;
#pragma unroll
        for (int k = 0; k < 8; ++k) Xs4[lane + (k << 6)] = Pa[lane + (k << 6)];
    }
    __syncthreads();
    {
        float tmp[32];
#pragma unroll
        for (int k = 0; k < 32; ++k) {
            int idx = lane + (k << 6);
            tmp[k] = (idx < 2032) ? (Xs[idx + 16] - Xs[idx]) : 0.0f;
        }
        __syncthreads();
#pragma unroll
        for (int k = 0; k < 32; ++k) {
            int idx = lane + (k << 6);
            if (idx < 2032) Xs[idx] = tmp[k];
        }
    }
    __syncthreads();
    float y0[16], y1[16];
    {
        const float* Qb = Q + b * 2048;
        const int r0 = lane << 1;
        const int r2 = (r0 + 2 > 127) ? 127 : (r0 + 2);
        const float4* A4 = (const float4*)(Qb + r0 * 16);
        const float4* B4 = (const float4*)(Qb + (r0 + 1) * 16);
        const float4* C4 = (const float4*)(Qb + r2 * 16);
#pragma unroll
        for (int q = 0; q < 4; ++q) {
            float4 ra = A4[q], rb = B4[q], rc = C4[q];
            y0[4*q+0] = rb.x - ra.x;  y1[4*q+0] = rc.x - rb.x;
            y0[4*q+1] = rb.y - ra.y;  y1[4*q+1] = rc.y - rb.y;
            y0[4*q+2] = rb.z - ra.z;  y1[4*q+2] = rc.z - rb.z;
            y0[4*q+3] = rb.w - ra.w;  y1[4*q+3] = rc.w - rb.w;
        }
    }
    float g_lo = 1.0f, g_hi = 1.0f;
    const bool last = (lane == 63);
    for (int r = 0; r < 127; ++r) {
        const float* xrow = Xs + r * 16;
        float s0 = -0.5f, s1 = -0.5f, t0 = -0.5f, t1 = -0.5f;
#pragma unroll
        for (int d = 0; d < 16; d += 2) {
            s0 = fmaf(xrow[d], y0[d], s0);   s1 = fmaf(xrow[d+1], y0[d+1], s1);
            t0 = fmaf(xrow[d], y1[d], t0);   t1 = fmaf(xrow[d+1], y1[d+1], t1);
        }
        const float i0 = s0 + s1, i1 = t0 + t1;
        const float gl = wave_shr1(g_hi, 1.0f);
        const float c0 = fmaf(gl, i0, g_lo);
        const float c1 = last ? 0.0f : fmaf(g_lo, i1, g_hi);
        const float S = wave_scan_incl(c0 + c1);
        g_lo = (S - c1) + 1.0f;
        g_hi = S + 1.0f;
    }
    const float kab = __builtin_bit_cast(float,
        __builtin_amdgcn_readlane(__builtin_bit_cast(int, g_lo), 63));
    if (lane == 0) ws[T] = weight * kab;
}

extern "C" void kernel_launch(void* const* d_in, const int* in_sizes, int n_in,
                              void* d_out, int out_size, void* d_ws, size_t ws_size,
                              hipStream_t stream) {
    const float* X = (const float*)d_in[0];
    const float* Y = (const float*)d_in[1];
    float* out = (float*)d_out;
    float* ws  = (float*)d_ws;

    const size_t need = (size_t)(WS_OUT_OFF + NOUT) * sizeof(float);
    if (ws_size >= need) {
        sig_diff<<<254, 256, 0, stream>>>(X, Y, ws);
        sig_pde2<<<NBLOCKS, 256, 0, stream>>>(ws, ws + WS_OUT_OFF);
        sig_reduce2<<<1, 256, 0, stream>>>(ws + WS_OUT_OFF, out, NOUT);
    } else {
        sig_pde_kernel<<<12288, 64, 0, stream>>>(X, Y, ws);
        sig_reduce2<<<1, 256, 0, stream>>>(ws, out, 12288);
    }
}